// Round 15
// baseline (194.310 us; speedup 1.0000x reference)
//
#include <hip/hip_runtime.h>

#define BB 4
#define NN 4096
#define CC 768
#define KNBR 4
constexpr float kEPS = 1e-5f;

typedef __attribute__((ext_vector_type(8))) short short8;
typedef __attribute__((ext_vector_type(4))) float f32x4;

__device__ __forceinline__ unsigned short f2b(float f) {  // fp32 -> bf16 RNE
  unsigned u = __float_as_uint(f);
  return (unsigned short)((u + 0x7fffu + ((u >> 16) & 1u)) >> 16);
}
__device__ __forceinline__ float b2f(unsigned short b) {
  return __uint_as_float((unsigned)b << 16);
}
__device__ __forceinline__ void gld16(const void* g, void* l) {
  __builtin_amdgcn_global_load_lds(
      (const __attribute__((address_space(1))) unsigned int*)g,
      (__attribute__((address_space(3))) unsigned int*)l, 16, 0, 0);
}

// orderable packed key: top-20 bits of sign-flipped fp32 | 12-bit index
__device__ __forceinline__ unsigned packkey(float v, unsigned idx) {
  unsigned u = __float_as_uint(v);
  unsigned k = u ^ (unsigned)(((int)u >> 31) | 0x80000000);
  return (k & 0xFFFFF000u) | idx;
}
__device__ __forceinline__ float unpackkey(unsigned key) {
  unsigned kb = key & 0xFFFFF000u;
  return __uint_as_float((kb & 0x80000000u) ? (kb ^ 0x80000000u) : ~kb);
}
// comparator: a=max, b=min (v_max_u32/v_min_u32)
__device__ __forceinline__ void csw(unsigned& a, unsigned& b) {
  unsigned hi = a > b ? a : b, lo = a > b ? b : a;
  a = hi; b = lo;
}
__device__ __forceinline__ void sort4(unsigned& a, unsigned& b, unsigned& c,
                                      unsigned& d) {
  csw(a, b); csw(c, d); csw(a, c); csw(b, d); csw(b, c);
}
// merge two desc-sorted quads, keep top-4 in a0..a3 (ILP-rich, no long chain)
__device__ __forceinline__ void mtop4(unsigned& a0, unsigned& a1, unsigned& a2,
                                      unsigned& a3, unsigned b0, unsigned b1,
                                      unsigned b2, unsigned b3) {
  a0 = a0 > b3 ? a0 : b3;
  a1 = a1 > b2 ? a1 : b2;
  a2 = a2 > b1 ? a2 : b1;
  a3 = a3 > b0 ? a3 : b0;
  csw(a0, a2); csw(a1, a3); csw(a0, a1); csw(a2, a3);
}

// bitonic merge of two desc-sorted 4-lists (self with partner at xor-dist off)
#define MERGE4(off)                                                   \
  {                                                                   \
    unsigned d0 = __shfl_xor((int)c0, off, 64);                       \
    unsigned d1 = __shfl_xor((int)c1, off, 64);                       \
    unsigned d2 = __shfl_xor((int)c2, off, 64);                       \
    unsigned d3 = __shfl_xor((int)c3, off, 64);                       \
    unsigned m0 = c0 > d3 ? c0 : d3;                                  \
    unsigned m1 = c1 > d2 ? c1 : d2;                                  \
    unsigned m2 = c2 > d1 ? c2 : d1;                                  \
    unsigned m3 = c3 > d0 ? c3 : d0;                                  \
    unsigned hi, lo;                                                  \
    hi = m0 > m2 ? m0 : m2; lo = m0 > m2 ? m2 : m0; m0 = hi; m2 = lo; \
    hi = m1 > m3 ? m1 : m3; lo = m1 > m3 ? m3 : m1; m1 = hi; m3 = lo; \
    hi = m0 > m1 ? m0 : m1; lo = m0 > m1 ? m1 : m0; m0 = hi; m1 = lo; \
    hi = m2 > m3 ? m2 : m3; lo = m2 > m3 ? m3 : m2; m2 = hi; m3 = lo; \
    c0 = m0; c1 = m1; c2 = m2; c3 = m3;                               \
  }

// ---------------- K1: hb = bf16(x + pos), sq[row] = sum(h^2) (fp32) --------
__global__ __launch_bounds__(192) void k_prep(const float* __restrict__ x,
                                              const float* __restrict__ pos,
                                              unsigned short* __restrict__ hb,
                                              float* __restrict__ sq) {
  int row = blockIdx.x;
  int t = threadIdx.x;
  const float4* x4 = reinterpret_cast<const float4*>(x + (size_t)row * CC);
  const float4* p4 = reinterpret_cast<const float4*>(pos + (size_t)row * CC);
  float4 a = x4[t], b = p4[t];
  float4 v;
  v.x = a.x + b.x; v.y = a.y + b.y; v.z = a.z + b.z; v.w = a.w + b.w;
  unsigned lo = (unsigned)f2b(v.x) | ((unsigned)f2b(v.y) << 16);
  unsigned hi = (unsigned)f2b(v.z) | ((unsigned)f2b(v.w) << 16);
  uint2 u; u.x = lo; u.y = hi;
  *reinterpret_cast<uint2*>(hb + (size_t)row * CC + t * 4) = u;
  float s = v.x * v.x + v.y * v.y + v.z * v.z + v.w * v.w;
  for (int off = 32; off > 0; off >>= 1) s += __shfl_down(s, off, 64);
  __shared__ float red[3];
  if ((t & 63) == 0) red[t >> 6] = s;
  __syncthreads();
  if (t == 0) sq[row] = red[0] + red[1] + red[2];
}

// ---------------- K2: weight prep: W1' (512x768 bf16), W2 bf16, BN2 affine --
__global__ __launch_bounds__(256) void k_wprep(const float* __restrict__ w1,
                                               const float* __restrict__ w2,
                                               const float* __restrict__ g2,
                                               const float* __restrict__ be2,
                                               const float* __restrict__ me2,
                                               const float* __restrict__ va2,
                                               unsigned short* __restrict__ w1b,
                                               unsigned short* __restrict__ w2b,
                                               float* __restrict__ s2,
                                               float* __restrict__ sh2) {
  int t = blockIdx.x * 256 + threadIdx.x;
  if (t < 512 * 768) {
    int o = t / 768, c = t % 768;
    float val = (o < 256) ? w1[(size_t)o * 1536 + c]
                          : (w1[(size_t)(o - 256) * 1536 + 768 + c] -
                             w1[(size_t)(o - 256) * 1536 + c]);
    w1b[t] = f2b(val);
  } else if (t < 512 * 768 + 768 * 256) {
    int u = t - 512 * 768;
    w2b[u] = f2b(w2[u]);
  } else if (t < 512 * 768 + 768 * 256 + 768) {
    int c = t - (512 * 768 + 768 * 256);
    float s = g2[c] * rsqrtf(va2[c] + kEPS);
    s2[c] = s;
    sh2[c] = be2[c] - me2[c] * s;
  }
}

// ---------------- K3: symmetric Gram MFMA, upper-triangle tiles ------------
// BK=32, 32KB dbuf -> 4 blocks/CU (vs R14's 64KB/2): same counted-vmcnt
// template (parameter change only), double residency to hide barriers.
// 64B rows: swizzle chunk ^= (row>>1)&3 on pre-swizzled source AND read.
__global__ __launch_bounds__(256) void k_gram(
    const unsigned short* __restrict__ hb, const float* __restrict__ sqv,
    unsigned* __restrict__ cand) {
  __shared__ unsigned short lds[16384];  // 32KB: buf0 [0..8191], buf1 [8192..]
  const int tid = threadIdx.x, lane = tid & 63, w = tid >> 6;
  const int wi = w >> 1, wj = w & 1;
  int nwg = gridDim.x, bid = blockIdx.x;
  int wg = (bid & 7) * (nwg >> 3) + (bid >> 3);  // XCD swizzle (2112%8==0)
  int b = wg / 528;
  int t = wg % 528;
  int it = 0;
  while (t >= 32 - it) { t -= 32 - it; ++it; }
  int jt = it + t;
  const unsigned short* H = hb + (size_t)b * NN * CC;
  const float* sqb = sqv + (size_t)b * NN;
  unsigned* cb = cand + (size_t)b * NN * 256;
  const size_t i0 = (size_t)it * 128, j0 = (size_t)jt * 128;

  const int srow = lane >> 2;   // 16 rows per 1KB load
  const int chp = lane & 3;     // 4 chunks of 16B per 64B row

  // hoisted staging bases (k0 added per step) + fixed linear LDS dests
  const unsigned short* gq[2];
  const unsigned short* gp[2];
  int dq[2], dp[2];
#pragma unroll
  for (int p = 0; p < 2; ++p) {
    int row = p * 64 + w * 16 + srow;
    int lc = chp ^ ((row >> 1) & 3);  // pre-swizzled source chunk
    gq[p] = H + (size_t)(j0 + row) * CC + lc * 8;
    gp[p] = H + (size_t)(i0 + row) * CC + lc * 8;
    dq[p] = row * 32 + chp * 8;          // linear: base + lane*16B
    dp[p] = 4096 + row * 32 + chp * 8;
  }
  // swizzled fragment read offsets (chunk = (lane>>4) ^ (row>>1)&3)
  int qoff[4], poff[4];
#pragma unroll
  for (int f = 0; f < 4; ++f) {
    int rq = wj * 64 + f * 16 + (lane & 15);
    qoff[f] = rq * 32 + (((lane >> 4) ^ ((rq >> 1) & 3)) * 8);
    int rp = wi * 64 + f * 16 + (lane & 15);
    poff[f] = 4096 + rp * 32 + (((lane >> 4) ^ ((rp >> 1) & 3)) * 8);
  }

  f32x4 acc[4][4];
#pragma unroll
  for (int fi = 0; fi < 4; ++fi)
#pragma unroll
    for (int fj = 0; fj < 4; ++fj) acc[fi][fj] = (f32x4){0.f, 0.f, 0.f, 0.f};

  auto STAGE = [&](int bufoff, int k0) {
#pragma unroll
    for (int p = 0; p < 2; ++p) gld16(gq[p] + k0, &lds[bufoff + dq[p]]);
#pragma unroll
    for (int p = 0; p < 2; ++p) gld16(gp[p] + k0, &lds[bufoff + dp[p]]);
  };
  auto COMPUTE = [&](int bufoff) {
    const unsigned short* L = lds + bufoff;
    short8 qf[4], pf[4];
#pragma unroll
    for (int f = 0; f < 4; ++f) {
      qf[f] = *(const short8*)&L[qoff[f]];
      pf[f] = *(const short8*)&L[poff[f]];
    }
#pragma unroll
    for (int fi = 0; fi < 4; ++fi)
#pragma unroll
      for (int fj = 0; fj < 4; ++fj)
        acc[fi][fj] = __builtin_amdgcn_mfma_f32_16x16x32_bf16(
            qf[fj], pf[fi], acc[fi][fj], 0, 0, 0);
  };

  STAGE(0, 0);
  for (int kt = 0; kt < 23; ++kt) {
    asm volatile("s_waitcnt lgkmcnt(0)" ::: "memory");  // own ds_reads done
    __builtin_amdgcn_s_barrier();   // all waves done reading buf[(kt+1)&1]
    STAGE(((kt + 1) & 1) * 8192, (kt + 1) * 32);
    asm volatile("s_waitcnt vmcnt(4)" ::: "memory");  // prev-stage loads landed
    __builtin_amdgcn_s_barrier();   // ... across all waves
    __builtin_amdgcn_sched_barrier(0);
    COMPUTE((kt & 1) * 8192);
  }
  asm volatile("s_waitcnt vmcnt(0)" ::: "memory");  // final stage landed
  __builtin_amdgcn_s_barrier();
  __builtin_amdgcn_sched_barrier(0);
  COMPUTE(8192);  // kt=23 -> buf1

  const int g = lane >> 4, l16 = lane & 15;

  // ---- row-pass: per-i top-4 over this tile's 128 j's (per 64-col seg) ----
#pragma unroll
  for (int fi = 0; fi < 4; ++fi) {
    unsigned c0, c1, c2, c3;
#pragma unroll
    for (int fj = 0; fj < 4; ++fj) {
      int jl = (int)j0 + wj * 64 + fj * 16 + g * 4;
      float4 s4 = *(const float4*)&sqb[jl];
      unsigned q0 = packkey(2.f * acc[fi][fj][0] - s4.x, (unsigned)(jl + 0));
      unsigned q1 = packkey(2.f * acc[fi][fj][1] - s4.y, (unsigned)(jl + 1));
      unsigned q2 = packkey(2.f * acc[fi][fj][2] - s4.z, (unsigned)(jl + 2));
      unsigned q3 = packkey(2.f * acc[fi][fj][3] - s4.w, (unsigned)(jl + 3));
      sort4(q0, q1, q2, q3);
      if (fj == 0) { c0 = q0; c1 = q1; c2 = q2; c3 = q3; }
      else mtop4(c0, c1, c2, c3, q0, q1, q2, q3);
    }
    MERGE4(16)
    MERGE4(32)
    if (g == fi) {
      size_t row = i0 + wi * 64 + fi * 16 + l16;
      uint4 o; o.x = c0; o.y = c1; o.z = c2; o.w = c3;
      *(uint4*)&cb[row * 256 + (size_t)(jt * 2 + wj) * 4] = o;
    }
  }

  // ---- col-pass (off-diagonal only): per-j top-4 over this wave's 64 i's,
  //      via per-wave LDS transpose [j][i ^ ((j&7)<<2)], two 32-j halves.
  //      tw uses full 32KB (both bufs dead after final COMPUTE + barrier). ---
  if (it != jt) {
    __syncthreads();  // full drain + exec sync: staging reads all complete
    float* tw = (float*)lds + w * 2048;  // 8KB per wave (wave-private)
    const int h = lane >> 5, jl = lane & 31;
    const int swz = (jl & 7) << 2;
#pragma unroll
    for (int half = 0; half < 2; ++half) {
      // intra-wave DS ordering guarantees write->read correctness; no barrier
#pragma unroll
      for (int fi = 0; fi < 4; ++fi)
#pragma unroll
        for (int fjl = 0; fjl < 2; ++fjl) {
          const int fj = half * 2 + fjl;
          const int iw = fi * 16 + l16;
#pragma unroll
          for (int r = 0; r < 4; ++r) {
            const int jh = fjl * 16 + g * 4 + r;
            tw[jh * 64 + (iw ^ ((jh & 7) << 2))] = acc[fi][fj][r];
          }
        }
      unsigned c0, c1, c2, c3;
#pragma unroll
      for (int ib = 0; ib < 32; ib += 4) {
        const f32x4 v4 = *(const f32x4*)&tw[jl * 64 + ((h * 32 + ib) ^ swz)];
        const int ig = (int)i0 + wi * 64 + h * 32 + ib;
        const float4 s4 = *(const float4*)&sqb[ig];
        unsigned q0 = packkey(2.f * v4[0] - s4.x, (unsigned)(ig + 0));
        unsigned q1 = packkey(2.f * v4[1] - s4.y, (unsigned)(ig + 1));
        unsigned q2 = packkey(2.f * v4[2] - s4.z, (unsigned)(ig + 2));
        unsigned q3 = packkey(2.f * v4[3] - s4.w, (unsigned)(ig + 3));
        sort4(q0, q1, q2, q3);
        if (ib == 0) { c0 = q0; c1 = q1; c2 = q2; c3 = q3; }
        else mtop4(c0, c1, c2, c3, q0, q1, q2, q3);
      }
      MERGE4(32)
      if (h == 0) {
        size_t jrow = j0 + wj * 64 + half * 32 + jl;
        uint4 o; o.x = c0; o.y = c1; o.z = c2; o.w = c3;
        *(uint4*)&cb[jrow * 256 + (size_t)(it * 2 + wi) * 4] = o;
      }
    }
  }
}

// ---------------- K4: bf16 MFMA GEMM (MLP layers) --------------------------
// MODE 1: bf16 out (T), K=768, grid 512 = 2 blocks/CU -> 64KB dbuf is
//         residency-free; counted-vmcnt schedule (R12-proven).
// MODE 2: BN2 + leaky-relu fp32 out (e0=s2, e1=sh2), K=256, grid 768 =
//         3 blocks/CU -> keep 32KB single-buffer (64KB would cap at 2).
template <int MODE>
__global__ __launch_bounds__(256) void k_mm(const unsigned short* __restrict__ P,
                                            const unsigned short* __restrict__ Q,
                                            void* __restrict__ outp,
                                            const float* __restrict__ e0,
                                            const float* __restrict__ e1,
                                            int K, int N, int jtiles) {
  __shared__ unsigned short lds[MODE == 1 ? 32768 : 16384];
  const int tid = threadIdx.x, lane = tid & 63, w = tid >> 6;
  const int wi = w >> 1, wj = w & 1;
  int nwg = gridDim.x, bid = blockIdx.x;
  int wg = (bid & 7) * (nwg >> 3) + (bid >> 3);
  int it = wg / jtiles, jt = wg % jtiles;
  const size_t i0 = (size_t)it * 128, j0 = (size_t)jt * 128;

  const int srow = lane >> 3;
  const int chp = lane & 7;
  const int lc = chp ^ srow;

  f32x4 acc[4][4];
#pragma unroll
  for (int fi = 0; fi < 4; ++fi)
#pragma unroll
    for (int fj = 0; fj < 4; ++fj) acc[fi][fj] = (f32x4){0.f, 0.f, 0.f, 0.f};

  auto STAGE = [&](int bufoff, int k0) {
#pragma unroll
    for (int p = 0; p < 4; ++p) {
      int row = p * 32 + w * 8 + srow;
      gld16(Q + ((size_t)(j0 + row) * K + k0 + lc * 8),
            &lds[bufoff + row * 64 + chp * 8]);
    }
#pragma unroll
    for (int p = 0; p < 4; ++p) {
      int row = p * 32 + w * 8 + srow;
      gld16(P + ((size_t)(i0 + row) * K + k0 + lc * 8),
            &lds[bufoff + 8192 + row * 64 + chp * 8]);
    }
  };
  auto COMPUTE = [&](int bufoff) {
    const unsigned short* L = lds + bufoff;
#pragma unroll
    for (int ks = 0; ks < 2; ++ks) {
      short8 qf[4], pf[4];
#pragma unroll
      for (int f = 0; f < 4; ++f) {
        int rq = wj * 64 + f * 16 + (lane & 15);
        int cq = (ks * 4 + (lane >> 4)) ^ (rq & 7);
        qf[f] = *(const short8*)&L[rq * 64 + cq * 8];
        int rp = wi * 64 + f * 16 + (lane & 15);
        int cp = (ks * 4 + (lane >> 4)) ^ (rp & 7);
        pf[f] = *(const short8*)&L[8192 + rp * 64 + cp * 8];
      }
#pragma unroll
      for (int fi = 0; fi < 4; ++fi)
#pragma unroll
        for (int fj = 0; fj < 4; ++fj)
          acc[fi][fj] = __builtin_amdgcn_mfma_f32_16x16x32_bf16(
              qf[fj], pf[fi], acc[fi][fj], 0, 0, 0);
    }
  };

  if constexpr (MODE == 1) {
    const int NT = K / 64;
    STAGE(0, 0);
    for (int kt = 0; kt < NT - 1; ++kt) {
      asm volatile("s_waitcnt lgkmcnt(0)" ::: "memory");
      __builtin_amdgcn_s_barrier();
      STAGE(((kt + 1) & 1) * 16384, (kt + 1) * 64);
      asm volatile("s_waitcnt vmcnt(8)" ::: "memory");
      __builtin_amdgcn_s_barrier();
      __builtin_amdgcn_sched_barrier(0);
      COMPUTE((kt & 1) * 16384);
    }
    asm volatile("s_waitcnt vmcnt(0)" ::: "memory");
    __builtin_amdgcn_s_barrier();
    __builtin_amdgcn_sched_barrier(0);
    COMPUTE(((NT - 1) & 1) * 16384);
  } else {
    for (int k0 = 0; k0 < K; k0 += 64) {
      __syncthreads();
      STAGE(0, k0);
      __syncthreads();
      COMPUTE(0);
    }
  }

#pragma unroll
  for (int fi = 0; fi < 4; ++fi) {
    size_t ig = i0 + wi * 64 + fi * 16 + (lane & 15);
#pragma unroll
    for (int fj = 0; fj < 4; ++fj) {
      size_t jg = j0 + wj * 64 + fj * 16 + ((lane >> 4) << 2);
      if (MODE == 1) {
        unsigned lo = (unsigned)f2b(acc[fi][fj][0]) |
                      ((unsigned)f2b(acc[fi][fj][1]) << 16);
        unsigned hi = (unsigned)f2b(acc[fi][fj][2]) |
                      ((unsigned)f2b(acc[fi][fj][3]) << 16);
        uint2 u; u.x = lo; u.y = hi;
        *(uint2*)((unsigned short*)outp + ig * (size_t)N + jg) = u;
      } else {
        f32x4 o4;
#pragma unroll
        for (int r = 0; r < 4; ++r) {
          size_t j = jg + r;
          float vv = acc[fi][fj][r] * e0[j] + e1[j];
          o4[r] = vv < 0.f ? 0.2f * vv : vv;
        }
        *(f32x4*)((float*)outp + ig * (size_t)N + jg) = o4;
      }
    }
  }
}

// ---------------- K5: adaptive top-k band + exact fp32 rescue --------------
__global__ __launch_bounds__(256) void k_topk(const unsigned* __restrict__ cand,
                                              const float* __restrict__ x,
                                              const float* __restrict__ pos,
                                              const float* __restrict__ sqv,
                                              int* __restrict__ idxb) {
  const int w = threadIdx.x >> 6, lane = threadIdx.x & 63;
  const int gn = blockIdx.x * 4 + w;
  const int b = gn >> 12, n = gn & 4095;
  const unsigned* crow = cand + ((size_t)b * NN + n) * 256;

  uint4 q = *(const uint4*)(crow + lane * 4);
  unsigned c0 = q.x, c1 = q.y, c2 = q.z, c3 = q.w;  // desc-sorted per slot

  unsigned keys[12];
  float dcut = -3.0e38f;
  int cnt = 0;
  bool stop = false;
#pragma unroll
  for (int r = 0; r < 12; ++r) {
    if (!stop) {
      unsigned best = c0;
#pragma unroll
      for (int off = 1; off < 64; off <<= 1) {
        unsigned o = (unsigned)__shfl_xor((int)best, off, 64);
        best = o > best ? o : best;
      }
      float val = unpackkey(best);
      if (r >= 4 && val < dcut) {
        stop = true;
      } else {
        keys[r] = best;
        cnt = r + 1;
        if (r == 3) dcut = val - 2.5f;
        if (c0 == best) { c0 = c1; c1 = c2; c2 = c3; c3 = 0; }
      }
    }
  }

  if (cnt == 4) {  // band empty beyond top-4: bf16 set provably exact
    if (lane == 0) {
      int4 o;
      o.x = (int)(keys[0] & 0xFFFu); o.y = (int)(keys[1] & 0xFFFu);
      o.z = (int)(keys[2] & 0xFFFu); o.w = (int)(keys[3] & 0xFFFu);
      *(int4*)(idxb + (size_t)gn * KNBR) = o;
    }
    return;  // wave-uniform
  }

  // exact fp32 re-rank of the cnt band candidates
  const float* xb = x + (size_t)b * NN * CC;
  const float* pb = pos + (size_t)b * NN * CC;
  const float* sqb = sqv + (size_t)b * NN;

  float hn[12];
  {
    const float4* xa = (const float4*)(xb + (size_t)n * CC + lane * 12);
    const float4* pa = (const float4*)(pb + (size_t)n * CC + lane * 12);
#pragma unroll
    for (int t = 0; t < 3; ++t) {
      float4 a = xa[t], bb = pa[t];
      hn[t * 4 + 0] = a.x + bb.x; hn[t * 4 + 1] = a.y + bb.y;
      hn[t * 4 + 2] = a.z + bb.z; hn[t * 4 + 3] = a.w + bb.w;
    }
  }
  float sqn = sqb[n];
  float b4v[4]; int b4m[4];
#pragma unroll
  for (int t = 0; t < 4; ++t) { b4v[t] = -3.0e38f; b4m[t] = 0x7fffffff; }

#pragma unroll
  for (int c = 0; c < 12; ++c) {
    if (c < cnt) {  // wave-uniform guard
      int m = (int)(keys[c] & 0xFFFu);
      const float4* xm = (const float4*)(xb + (size_t)m * CC + lane * 12);
      const float4* pm = (const float4*)(pb + (size_t)m * CC + lane * 12);
      float d = 0.f;
#pragma unroll
      for (int t = 0; t < 3; ++t) {
        float4 a = xm[t], bb = pm[t];
        d = fmaf(hn[t * 4 + 0], a.x + bb.x, d);
        d = fmaf(hn[t * 4 + 1], a.y + bb.y, d);
        d = fmaf(hn[t * 4 + 2], a.z + bb.z, d);
        d = fmaf(hn[t * 4 + 3], a.w + bb.w, d);
      }
#pragma unroll
      for (int off = 1; off < 64; off <<= 1) d += __shfl_xor(d, off, 64);
      float val = (2.f * d - sqn) - sqb[m];
      if (val > b4v[3] || (val == b4v[3] && m < b4m[3])) {
        b4v[3] = val; b4m[3] = m;
#pragma unroll
        for (int t = 3; t > 0; --t)
          if (b4v[t] > b4v[t - 1] ||
              (b4v[t] == b4v[t - 1] && b4m[t] < b4m[t - 1])) {
            float tv = b4v[t]; b4v[t] = b4v[t - 1]; b4v[t - 1] = tv;
            int tm = b4m[t]; b4m[t] = b4m[t - 1]; b4m[t - 1] = tm;
          }
      }
    }
  }
  if (lane == 0) {
    int4 o; o.x = b4m[0]; o.y = b4m[1]; o.z = b4m[2]; o.w = b4m[3];
    *(int4*)(idxb + (size_t)gn * KNBR) = o;
  }
}

// ---------------- K6: gather + BN1 + LReLU + max over K (bf16 T) -----------
__global__ __launch_bounds__(256) void k_pool(const unsigned short* __restrict__ Tb,
                                              const int* __restrict__ idx,
                                              const float* __restrict__ g1,
                                              const float* __restrict__ b1,
                                              const float* __restrict__ m1,
                                              const float* __restrict__ v1,
                                              unsigned short* __restrict__ pooledb) {
  int bn = blockIdx.x;
  int b = bn >> 12;
  int o = threadIdx.x;
  float s = g1[o] * rsqrtf(v1[o] + kEPS);
  float sh = b1[o] - m1[o] * s;
  float Pp = b2f(Tb[(size_t)bn * 512 + 256 + o]);
  const int* ix = idx + (size_t)bn * KNBR;
  float mx = -3.0e38f;
#pragma unroll
  for (int k = 0; k < KNBR; k++) {
    int m = ix[k];
    float gg = b2f(Tb[((size_t)b * NN + m) * 512 + o]);
    float y = (gg + Pp) * s + sh;
    y = y < 0.f ? 0.2f * y : y;
    mx = fmaxf(mx, y);
  }
  pooledb[(size_t)bn * 256 + o] = f2b(mx);
}

extern "C" void kernel_launch(void* const* d_in, const int* in_sizes, int n_in,
                              void* d_out, int out_size, void* d_ws,
                              size_t ws_size, hipStream_t stream) {
  const float* x = (const float*)d_in[0];
  const float* pos = (const float*)d_in[1];
  const float* w1 = (const float*)d_in[2];
  const float* gamma1 = (const float*)d_in[3];
  const float* beta1 = (const float*)d_in[4];
  const float* mean1 = (const float*)d_in[5];
  const float* var1 = (const float*)d_in[6];
  const float* w2 = (const float*)d_in[7];
  const float* gamma2 = (const float*)d_in[8];
  const float* beta2 = (const float*)d_in[9];
  const float* mean2 = (const float*)d_in[10];
  const float* var2 = (const float*)d_in[11];
  float* out = (float*)d_out;

  // ws layout (~70 MB): cand (16.8MB u32) and Tb (16.8MB u16) both live.
  float* ws = (float*)d_ws;
  float* s2 = ws;                                            // 768
  float* sh2 = s2 + 768;                                     // 768
  float* sqv = sh2 + 768;                                    // 16384
  unsigned short* w1b = (unsigned short*)(sqv + 16384);      // 512*768 u16
  unsigned short* w2b = w1b + 512 * 768;                     // 768*256 u16
  int* idx = (int*)(w2b + 768 * 256);                        // 65536 int
  unsigned short* hb = (unsigned short*)(idx + 65536);       // 4*4096*768 u16
  unsigned short* pooledb = hb + (size_t)BB * NN * CC;       // 4*4096*256 u16
  unsigned* cand = (unsigned*)(pooledb + (size_t)BB * NN * 256);  // 4.19M u32
  unsigned short* Tb = (unsigned short*)(cand + (size_t)BB * NN * 256);

  k_prep<<<BB * NN, 192, 0, stream>>>(x, pos, hb, sqv);
  k_wprep<<<2307, 256, 0, stream>>>(w1, w2, gamma2, beta2, mean2, var2,
                                    w1b, w2b, s2, sh2);
  k_gram<<<BB * 528, 256, 0, stream>>>(hb, sqv, cand);
  k_topk<<<BB * NN / 4, 256, 0, stream>>>(cand, x, pos, sqv, idx);
  k_mm<1><<<512, 256, 0, stream>>>(hb, w1b, Tb, nullptr, nullptr, CC, 512, 4);
  k_pool<<<BB * NN, 256, 0, stream>>>(Tb, idx, gamma1, beta1, mean1, var1, pooledb);
  k_mm<2><<<768, 256, 0, stream>>>(pooledb, w2b, out, s2, sh2, 256, CC, 6);
}

// Round 16
// 183.193 us; speedup vs baseline: 1.0607x; 1.0607x over previous
//
#include <hip/hip_runtime.h>

#define BB 4
#define NN 4096
#define CC 768
#define KNBR 4
constexpr float kEPS = 1e-5f;

typedef __attribute__((ext_vector_type(8))) short short8;
typedef __attribute__((ext_vector_type(4))) float f32x4;

__device__ __forceinline__ unsigned short f2b(float f) {  // fp32 -> bf16 RNE
  unsigned u = __float_as_uint(f);
  return (unsigned short)((u + 0x7fffu + ((u >> 16) & 1u)) >> 16);
}
__device__ __forceinline__ float b2f(unsigned short b) {
  return __uint_as_float((unsigned)b << 16);
}
__device__ __forceinline__ void gld16(const void* g, void* l) {
  __builtin_amdgcn_global_load_lds(
      (const __attribute__((address_space(1))) unsigned int*)g,
      (__attribute__((address_space(3))) unsigned int*)l, 16, 0, 0);
}

// orderable packed key: top-20 bits of sign-flipped fp32 | 12-bit index
__device__ __forceinline__ unsigned packkey(float v, unsigned idx) {
  unsigned u = __float_as_uint(v);
  unsigned k = u ^ (unsigned)(((int)u >> 31) | 0x80000000);
  return (k & 0xFFFFF000u) | idx;
}
__device__ __forceinline__ float unpackkey(unsigned key) {
  unsigned kb = key & 0xFFFFF000u;
  return __uint_as_float((kb & 0x80000000u) ? (kb ^ 0x80000000u) : ~kb);
}
// comparator: a=max, b=min (v_max_u32/v_min_u32)
__device__ __forceinline__ void csw(unsigned& a, unsigned& b) {
  unsigned hi = a > b ? a : b, lo = a > b ? b : a;
  a = hi; b = lo;
}
__device__ __forceinline__ void sort4(unsigned& a, unsigned& b, unsigned& c,
                                      unsigned& d) {
  csw(a, b); csw(c, d); csw(a, c); csw(b, d); csw(b, c);
}
// merge two desc-sorted quads, keep top-4 in a0..a3 (ILP-rich, no long chain)
__device__ __forceinline__ void mtop4(unsigned& a0, unsigned& a1, unsigned& a2,
                                      unsigned& a3, unsigned b0, unsigned b1,
                                      unsigned b2, unsigned b3) {
  a0 = a0 > b3 ? a0 : b3;
  a1 = a1 > b2 ? a1 : b2;
  a2 = a2 > b1 ? a2 : b1;
  a3 = a3 > b0 ? a3 : b0;
  csw(a0, a2); csw(a1, a3); csw(a0, a1); csw(a2, a3);
}

// bitonic merge of two desc-sorted 4-lists (self with partner at xor-dist off)
#define MERGE4(off)                                                   \
  {                                                                   \
    unsigned d0 = __shfl_xor((int)c0, off, 64);                       \
    unsigned d1 = __shfl_xor((int)c1, off, 64);                       \
    unsigned d2 = __shfl_xor((int)c2, off, 64);                       \
    unsigned d3 = __shfl_xor((int)c3, off, 64);                       \
    unsigned m0 = c0 > d3 ? c0 : d3;                                  \
    unsigned m1 = c1 > d2 ? c1 : d2;                                  \
    unsigned m2 = c2 > d1 ? c2 : d1;                                  \
    unsigned m3 = c3 > d0 ? c3 : d0;                                  \
    unsigned hi, lo;                                                  \
    hi = m0 > m2 ? m0 : m2; lo = m0 > m2 ? m2 : m0; m0 = hi; m2 = lo; \
    hi = m1 > m3 ? m1 : m3; lo = m1 > m3 ? m3 : m1; m1 = hi; m3 = lo; \
    hi = m0 > m1 ? m0 : m1; lo = m0 > m1 ? m1 : m0; m0 = hi; m1 = lo; \
    hi = m2 > m3 ? m2 : m3; lo = m2 > m3 ? m3 : m2; m2 = hi; m3 = lo; \
    c0 = m0; c1 = m1; c2 = m2; c3 = m3;                               \
  }

// ---------------- K1: hb = bf16(x + pos), sq[row] = sum(h^2) (fp32) --------
__global__ __launch_bounds__(192) void k_prep(const float* __restrict__ x,
                                              const float* __restrict__ pos,
                                              unsigned short* __restrict__ hb,
                                              float* __restrict__ sq) {
  int row = blockIdx.x;
  int t = threadIdx.x;
  const float4* x4 = reinterpret_cast<const float4*>(x + (size_t)row * CC);
  const float4* p4 = reinterpret_cast<const float4*>(pos + (size_t)row * CC);
  float4 a = x4[t], b = p4[t];
  float4 v;
  v.x = a.x + b.x; v.y = a.y + b.y; v.z = a.z + b.z; v.w = a.w + b.w;
  unsigned lo = (unsigned)f2b(v.x) | ((unsigned)f2b(v.y) << 16);
  unsigned hi = (unsigned)f2b(v.z) | ((unsigned)f2b(v.w) << 16);
  uint2 u; u.x = lo; u.y = hi;
  *reinterpret_cast<uint2*>(hb + (size_t)row * CC + t * 4) = u;
  float s = v.x * v.x + v.y * v.y + v.z * v.z + v.w * v.w;
  for (int off = 32; off > 0; off >>= 1) s += __shfl_down(s, off, 64);
  __shared__ float red[3];
  if ((t & 63) == 0) red[t >> 6] = s;
  __syncthreads();
  if (t == 0) sq[row] = red[0] + red[1] + red[2];
}

// ---------------- K2: weight prep: W1' (512x768 bf16), W2 bf16, BN2 affine --
__global__ __launch_bounds__(256) void k_wprep(const float* __restrict__ w1,
                                               const float* __restrict__ w2,
                                               const float* __restrict__ g2,
                                               const float* __restrict__ be2,
                                               const float* __restrict__ me2,
                                               const float* __restrict__ va2,
                                               unsigned short* __restrict__ w1b,
                                               unsigned short* __restrict__ w2b,
                                               float* __restrict__ s2,
                                               float* __restrict__ sh2) {
  int t = blockIdx.x * 256 + threadIdx.x;
  if (t < 512 * 768) {
    int o = t / 768, c = t % 768;
    float val = (o < 256) ? w1[(size_t)o * 1536 + c]
                          : (w1[(size_t)(o - 256) * 1536 + 768 + c] -
                             w1[(size_t)(o - 256) * 1536 + c]);
    w1b[t] = f2b(val);
  } else if (t < 512 * 768 + 768 * 256) {
    int u = t - 512 * 768;
    w2b[u] = f2b(w2[u]);
  } else if (t < 512 * 768 + 768 * 256 + 768) {
    int c = t - (512 * 768 + 768 * 256);
    float s = g2[c] * rsqrtf(va2[c] + kEPS);
    s2[c] = s;
    sh2[c] = be2[c] - me2[c] * s;
  }
}

// ---------------- K3: symmetric Gram MFMA, upper-triangle tiles ------------
// K-loop: double-buffered staging, counted vmcnt(8) prefetch (T3-min+T4).
__global__ __launch_bounds__(256) void k_gram(
    const unsigned short* __restrict__ hb, const float* __restrict__ sqv,
    unsigned* __restrict__ cand) {
  __shared__ unsigned short lds[32768];  // 64KB: buf0 [0..16383], buf1 [16384..]
  const int tid = threadIdx.x, lane = tid & 63, w = tid >> 6;
  const int wi = w >> 1, wj = w & 1;
  int nwg = gridDim.x, bid = blockIdx.x;
  int wg = (bid & 7) * (nwg >> 3) + (bid >> 3);  // XCD swizzle (2112%8==0)
  int b = wg / 528;
  int t = wg % 528;
  int it = 0;
  while (t >= 32 - it) { t -= 32 - it; ++it; }
  int jt = it + t;
  const unsigned short* H = hb + (size_t)b * NN * CC;
  const float* sqb = sqv + (size_t)b * NN;
  unsigned* cb = cand + (size_t)b * NN * 256;
  const size_t i0 = (size_t)it * 128, j0 = (size_t)jt * 128;

  const int srow = lane >> 3;
  const int chp = lane & 7;
  const int lc = chp ^ srow;

  // hoisted staging bases (k0 added per step) + fixed LDS dest offsets
  const unsigned short* gq[4];
  const unsigned short* gp[4];
  int dq[4], dp[4];
#pragma unroll
  for (int p = 0; p < 4; ++p) {
    int row = p * 32 + w * 8 + srow;
    gq[p] = H + (size_t)(j0 + row) * CC + lc * 8;
    gp[p] = H + (size_t)(i0 + row) * CC + lc * 8;
    dq[p] = row * 64 + chp * 8;
    dp[p] = 8192 + row * 64 + chp * 8;
  }
  // hoisted swizzled fragment read offsets
  int qoff[2][4], poff[2][4];
#pragma unroll
  for (int ks = 0; ks < 2; ++ks)
#pragma unroll
    for (int f = 0; f < 4; ++f) {
      int rq = wj * 64 + f * 16 + (lane & 15);
      qoff[ks][f] = rq * 64 + (((ks * 4 + (lane >> 4)) ^ (rq & 7)) * 8);
      int rp = wi * 64 + f * 16 + (lane & 15);
      poff[ks][f] = 8192 + rp * 64 + (((ks * 4 + (lane >> 4)) ^ (rp & 7)) * 8);
    }

  f32x4 acc[4][4];
#pragma unroll
  for (int fi = 0; fi < 4; ++fi)
#pragma unroll
    for (int fj = 0; fj < 4; ++fj) acc[fi][fj] = (f32x4){0.f, 0.f, 0.f, 0.f};

  auto STAGE = [&](int bufoff, int k0) {
#pragma unroll
    for (int p = 0; p < 4; ++p) gld16(gq[p] + k0, &lds[bufoff + dq[p]]);
#pragma unroll
    for (int p = 0; p < 4; ++p) gld16(gp[p] + k0, &lds[bufoff + dp[p]]);
  };
  auto COMPUTE = [&](int bufoff) {
    const unsigned short* L = lds + bufoff;
#pragma unroll
    for (int ks = 0; ks < 2; ++ks) {
      short8 qf[4], pf[4];
#pragma unroll
      for (int f = 0; f < 4; ++f) {
        qf[f] = *(const short8*)&L[qoff[ks][f]];
        pf[f] = *(const short8*)&L[poff[ks][f]];
      }
#pragma unroll
      for (int fi = 0; fi < 4; ++fi)
#pragma unroll
        for (int fj = 0; fj < 4; ++fj)
          acc[fi][fj] = __builtin_amdgcn_mfma_f32_16x16x32_bf16(
              qf[fj], pf[fi], acc[fi][fj], 0, 0, 0);
    }
  };

  STAGE(0, 0);
  for (int kt = 0; kt < 11; ++kt) {
    asm volatile("s_waitcnt lgkmcnt(0)" ::: "memory");  // own ds_reads done
    __builtin_amdgcn_s_barrier();   // all waves done reading buf[(kt+1)&1]
    STAGE(((kt + 1) & 1) * 16384, (kt + 1) * 64);
    asm volatile("s_waitcnt vmcnt(8)" ::: "memory");  // prev-stage loads landed
    __builtin_amdgcn_s_barrier();   // ... across all waves
    __builtin_amdgcn_sched_barrier(0);
    COMPUTE((kt & 1) * 16384);
  }
  asm volatile("s_waitcnt vmcnt(0)" ::: "memory");  // final stage landed
  __builtin_amdgcn_s_barrier();
  __builtin_amdgcn_sched_barrier(0);
  COMPUTE(16384);  // kt=11 -> buf1

  const int g = lane >> 4, l16 = lane & 15;

  // ---- row-pass: per-i top-4 over this tile's 128 j's (per 64-col seg) ----
#pragma unroll
  for (int fi = 0; fi < 4; ++fi) {
    unsigned c0, c1, c2, c3;
#pragma unroll
    for (int fj = 0; fj < 4; ++fj) {
      int jl = (int)j0 + wj * 64 + fj * 16 + g * 4;
      float4 s4 = *(const float4*)&sqb[jl];
      unsigned q0 = packkey(2.f * acc[fi][fj][0] - s4.x, (unsigned)(jl + 0));
      unsigned q1 = packkey(2.f * acc[fi][fj][1] - s4.y, (unsigned)(jl + 1));
      unsigned q2 = packkey(2.f * acc[fi][fj][2] - s4.z, (unsigned)(jl + 2));
      unsigned q3 = packkey(2.f * acc[fi][fj][3] - s4.w, (unsigned)(jl + 3));
      sort4(q0, q1, q2, q3);
      if (fj == 0) { c0 = q0; c1 = q1; c2 = q2; c3 = q3; }
      else mtop4(c0, c1, c2, c3, q0, q1, q2, q3);
    }
    MERGE4(16)
    MERGE4(32)
    if (g == fi) {
      size_t row = i0 + wi * 64 + fi * 16 + l16;
      uint4 o; o.x = c0; o.y = c1; o.z = c2; o.w = c3;
      *(uint4*)&cb[row * 256 + (size_t)(jt * 2 + wj) * 4] = o;
    }
  }

  // ---- col-pass (off-diagonal only): per-j top-4 over this wave's 64 i's,
  //      via per-wave LDS transpose [j][i ^ ((j&7)<<2)], two 32-j halves.
  //      tw aliases buf0 (last COMPUTE read buf1 -> disjoint). ---------------
  if (it != jt) {
    __syncthreads();  // full drain + exec sync: staging reads all complete
    float* tw = (float*)lds + w * 2048;  // 8KB per wave (wave-private)
    const int h = lane >> 5, jl = lane & 31;
    const int swz = (jl & 7) << 2;
#pragma unroll
    for (int half = 0; half < 2; ++half) {
      // intra-wave DS ordering guarantees write->read correctness; no barrier
#pragma unroll
      for (int fi = 0; fi < 4; ++fi)
#pragma unroll
        for (int fjl = 0; fjl < 2; ++fjl) {
          const int fj = half * 2 + fjl;
          const int iw = fi * 16 + l16;
#pragma unroll
          for (int r = 0; r < 4; ++r) {
            const int jh = fjl * 16 + g * 4 + r;
            tw[jh * 64 + (iw ^ ((jh & 7) << 2))] = acc[fi][fj][r];
          }
        }
      unsigned c0, c1, c2, c3;
#pragma unroll
      for (int ib = 0; ib < 32; ib += 4) {
        const f32x4 v4 = *(const f32x4*)&tw[jl * 64 + ((h * 32 + ib) ^ swz)];
        const int ig = (int)i0 + wi * 64 + h * 32 + ib;
        const float4 s4 = *(const float4*)&sqb[ig];
        unsigned q0 = packkey(2.f * v4[0] - s4.x, (unsigned)(ig + 0));
        unsigned q1 = packkey(2.f * v4[1] - s4.y, (unsigned)(ig + 1));
        unsigned q2 = packkey(2.f * v4[2] - s4.z, (unsigned)(ig + 2));
        unsigned q3 = packkey(2.f * v4[3] - s4.w, (unsigned)(ig + 3));
        sort4(q0, q1, q2, q3);
        if (ib == 0) { c0 = q0; c1 = q1; c2 = q2; c3 = q3; }
        else mtop4(c0, c1, c2, c3, q0, q1, q2, q3);
      }
      MERGE4(32)
      if (h == 0) {
        size_t jrow = j0 + wj * 64 + half * 32 + jl;
        uint4 o; o.x = c0; o.y = c1; o.z = c2; o.w = c3;
        *(uint4*)&cb[jrow * 256 + (size_t)(it * 2 + wi) * 4] = o;
      }
    }
  }
}

// ---------------- K4: bf16 MFMA GEMM (MLP layers) --------------------------
// MODE 1: bf16 out (T), K=768, grid 512 = 2 blocks/CU -> 64KB dbuf is
//         residency-free; counted-vmcnt schedule (R12-proven).
// MODE 2: BN2 + leaky-relu fp32 out (e0=s2, e1=sh2), K=256, grid 768 =
//         3 blocks/CU -> keep 32KB single-buffer (64KB would cap at 2).
template <int MODE>
__global__ __launch_bounds__(256) void k_mm(const unsigned short* __restrict__ P,
                                            const unsigned short* __restrict__ Q,
                                            void* __restrict__ outp,
                                            const float* __restrict__ e0,
                                            const float* __restrict__ e1,
                                            int K, int N, int jtiles) {
  __shared__ unsigned short lds[MODE == 1 ? 32768 : 16384];
  const int tid = threadIdx.x, lane = tid & 63, w = tid >> 6;
  const int wi = w >> 1, wj = w & 1;
  int nwg = gridDim.x, bid = blockIdx.x;
  int wg = (bid & 7) * (nwg >> 3) + (bid >> 3);
  int it = wg / jtiles, jt = wg % jtiles;
  const size_t i0 = (size_t)it * 128, j0 = (size_t)jt * 128;

  const int srow = lane >> 3;
  const int chp = lane & 7;
  const int lc = chp ^ srow;

  f32x4 acc[4][4];
#pragma unroll
  for (int fi = 0; fi < 4; ++fi)
#pragma unroll
    for (int fj = 0; fj < 4; ++fj) acc[fi][fj] = (f32x4){0.f, 0.f, 0.f, 0.f};

  auto STAGE = [&](int bufoff, int k0) {
#pragma unroll
    for (int p = 0; p < 4; ++p) {
      int row = p * 32 + w * 8 + srow;
      gld16(Q + ((size_t)(j0 + row) * K + k0 + lc * 8),
            &lds[bufoff + row * 64 + chp * 8]);
    }
#pragma unroll
    for (int p = 0; p < 4; ++p) {
      int row = p * 32 + w * 8 + srow;
      gld16(P + ((size_t)(i0 + row) * K + k0 + lc * 8),
            &lds[bufoff + 8192 + row * 64 + chp * 8]);
    }
  };
  auto COMPUTE = [&](int bufoff) {
    const unsigned short* L = lds + bufoff;
#pragma unroll
    for (int ks = 0; ks < 2; ++ks) {
      short8 qf[4], pf[4];
#pragma unroll
      for (int f = 0; f < 4; ++f) {
        int rq = wj * 64 + f * 16 + (lane & 15);
        int cq = (ks * 4 + (lane >> 4)) ^ (rq & 7);
        qf[f] = *(const short8*)&L[rq * 64 + cq * 8];
        int rp = wi * 64 + f * 16 + (lane & 15);
        int cp = (ks * 4 + (lane >> 4)) ^ (rp & 7);
        pf[f] = *(const short8*)&L[8192 + rp * 64 + cp * 8];
      }
#pragma unroll
      for (int fi = 0; fi < 4; ++fi)
#pragma unroll
        for (int fj = 0; fj < 4; ++fj)
          acc[fi][fj] = __builtin_amdgcn_mfma_f32_16x16x32_bf16(
              qf[fj], pf[fi], acc[fi][fj], 0, 0, 0);
    }
  };

  if constexpr (MODE == 1) {
    const int NT = K / 64;
    STAGE(0, 0);
    for (int kt = 0; kt < NT - 1; ++kt) {
      asm volatile("s_waitcnt lgkmcnt(0)" ::: "memory");
      __builtin_amdgcn_s_barrier();
      STAGE(((kt + 1) & 1) * 16384, (kt + 1) * 64);
      asm volatile("s_waitcnt vmcnt(8)" ::: "memory");
      __builtin_amdgcn_s_barrier();
      __builtin_amdgcn_sched_barrier(0);
      COMPUTE((kt & 1) * 16384);
    }
    asm volatile("s_waitcnt vmcnt(0)" ::: "memory");
    __builtin_amdgcn_s_barrier();
    __builtin_amdgcn_sched_barrier(0);
    COMPUTE(((NT - 1) & 1) * 16384);
  } else {
    for (int k0 = 0; k0 < K; k0 += 64) {
      __syncthreads();
      STAGE(0, k0);
      __syncthreads();
      COMPUTE(0);
    }
  }

#pragma unroll
  for (int fi = 0; fi < 4; ++fi) {
    size_t ig = i0 + wi * 64 + fi * 16 + (lane & 15);
#pragma unroll
    for (int fj = 0; fj < 4; ++fj) {
      size_t jg = j0 + wj * 64 + fj * 16 + ((lane >> 4) << 2);
      if (MODE == 1) {
        unsigned lo = (unsigned)f2b(acc[fi][fj][0]) |
                      ((unsigned)f2b(acc[fi][fj][1]) << 16);
        unsigned hi = (unsigned)f2b(acc[fi][fj][2]) |
                      ((unsigned)f2b(acc[fi][fj][3]) << 16);
        uint2 u; u.x = lo; u.y = hi;
        *(uint2*)((unsigned short*)outp + ig * (size_t)N + jg) = u;
      } else {
        f32x4 o4;
#pragma unroll
        for (int r = 0; r < 4; ++r) {
          size_t j = jg + r;
          float vv = acc[fi][fj][r] * e0[j] + e1[j];
          o4[r] = vv < 0.f ? 0.2f * vv : vv;
        }
        *(f32x4*)((float*)outp + ig * (size_t)N + jg) = o4;
      }
    }
  }
}

// ---------------- K5: adaptive top-k band + exact fp32 rescue --------------
__global__ __launch_bounds__(256) void k_topk(const unsigned* __restrict__ cand,
                                              const float* __restrict__ x,
                                              const float* __restrict__ pos,
                                              const float* __restrict__ sqv,
                                              int* __restrict__ idxb) {
  const int w = threadIdx.x >> 6, lane = threadIdx.x & 63;
  const int gn = blockIdx.x * 4 + w;
  const int b = gn >> 12, n = gn & 4095;
  const unsigned* crow = cand + ((size_t)b * NN + n) * 256;

  uint4 q = *(const uint4*)(crow + lane * 4);
  unsigned c0 = q.x, c1 = q.y, c2 = q.z, c3 = q.w;  // desc-sorted per slot

  unsigned keys[12];
  float dcut = -3.0e38f;
  int cnt = 0;
  bool stop = false;
#pragma unroll
  for (int r = 0; r < 12; ++r) {
    if (!stop) {
      unsigned best = c0;
#pragma unroll
      for (int off = 1; off < 64; off <<= 1) {
        unsigned o = (unsigned)__shfl_xor((int)best, off, 64);
        best = o > best ? o : best;
      }
      float val = unpackkey(best);
      if (r >= 4 && val < dcut) {
        stop = true;
      } else {
        keys[r] = best;
        cnt = r + 1;
        if (r == 3) dcut = val - 2.5f;
        if (c0 == best) { c0 = c1; c1 = c2; c2 = c3; c3 = 0; }
      }
    }
  }

  if (cnt == 4) {  // band empty beyond top-4: bf16 set provably exact
    if (lane == 0) {
      int4 o;
      o.x = (int)(keys[0] & 0xFFFu); o.y = (int)(keys[1] & 0xFFFu);
      o.z = (int)(keys[2] & 0xFFFu); o.w = (int)(keys[3] & 0xFFFu);
      *(int4*)(idxb + (size_t)gn * KNBR) = o;
    }
    return;  // wave-uniform
  }

  // exact fp32 re-rank of the cnt band candidates
  const float* xb = x + (size_t)b * NN * CC;
  const float* pb = pos + (size_t)b * NN * CC;
  const float* sqb = sqv + (size_t)b * NN;

  float hn[12];
  {
    const float4* xa = (const float4*)(xb + (size_t)n * CC + lane * 12);
    const float4* pa = (const float4*)(pb + (size_t)n * CC + lane * 12);
#pragma unroll
    for (int t = 0; t < 3; ++t) {
      float4 a = xa[t], bb = pa[t];
      hn[t * 4 + 0] = a.x + bb.x; hn[t * 4 + 1] = a.y + bb.y;
      hn[t * 4 + 2] = a.z + bb.z; hn[t * 4 + 3] = a.w + bb.w;
    }
  }
  float sqn = sqb[n];
  float b4v[4]; int b4m[4];
#pragma unroll
  for (int t = 0; t < 4; ++t) { b4v[t] = -3.0e38f; b4m[t] = 0x7fffffff; }

#pragma unroll
  for (int c = 0; c < 12; ++c) {
    if (c < cnt) {  // wave-uniform guard
      int m = (int)(keys[c] & 0xFFFu);
      const float4* xm = (const float4*)(xb + (size_t)m * CC + lane * 12);
      const float4* pm = (const float4*)(pb + (size_t)m * CC + lane * 12);
      float d = 0.f;
#pragma unroll
      for (int t = 0; t < 3; ++t) {
        float4 a = xm[t], bb = pm[t];
        d = fmaf(hn[t * 4 + 0], a.x + bb.x, d);
        d = fmaf(hn[t * 4 + 1], a.y + bb.y, d);
        d = fmaf(hn[t * 4 + 2], a.z + bb.z, d);
        d = fmaf(hn[t * 4 + 3], a.w + bb.w, d);
      }
#pragma unroll
      for (int off = 1; off < 64; off <<= 1) d += __shfl_xor(d, off, 64);
      float val = (2.f * d - sqn) - sqb[m];
      if (val > b4v[3] || (val == b4v[3] && m < b4m[3])) {
        b4v[3] = val; b4m[3] = m;
#pragma unroll
        for (int t = 3; t > 0; --t)
          if (b4v[t] > b4v[t - 1] ||
              (b4v[t] == b4v[t - 1] && b4m[t] < b4m[t - 1])) {
            float tv = b4v[t]; b4v[t] = b4v[t - 1]; b4v[t - 1] = tv;
            int tm = b4m[t]; b4m[t] = b4m[t - 1]; b4m[t - 1] = tm;
          }
      }
    }
  }
  if (lane == 0) {
    int4 o; o.x = b4m[0]; o.y = b4m[1]; o.z = b4m[2]; o.w = b4m[3];
    *(int4*)(idxb + (size_t)gn * KNBR) = o;
  }
}

// ---------------- K6: gather + BN1 + LReLU + max over K (bf16 T) -----------
__global__ __launch_bounds__(256) void k_pool(const unsigned short* __restrict__ Tb,
                                              const int* __restrict__ idx,
                                              const float* __restrict__ g1,
                                              const float* __restrict__ b1,
                                              const float* __restrict__ m1,
                                              const float* __restrict__ v1,
                                              unsigned short* __restrict__ pooledb) {
  int bn = blockIdx.x;
  int b = bn >> 12;
  int o = threadIdx.x;
  float s = g1[o] * rsqrtf(v1[o] + kEPS);
  float sh = b1[o] - m1[o] * s;
  float Pp = b2f(Tb[(size_t)bn * 512 + 256 + o]);
  const int* ix = idx + (size_t)bn * KNBR;
  float mx = -3.0e38f;
#pragma unroll
  for (int k = 0; k < KNBR; k++) {
    int m = ix[k];
    float gg = b2f(Tb[((size_t)b * NN + m) * 512 + o]);
    float y = (gg + Pp) * s + sh;
    y = y < 0.f ? 0.2f * y : y;
    mx = fmaxf(mx, y);
  }
  pooledb[(size_t)bn * 256 + o] = f2b(mx);
}

extern "C" void kernel_launch(void* const* d_in, const int* in_sizes, int n_in,
                              void* d_out, int out_size, void* d_ws,
                              size_t ws_size, hipStream_t stream) {
  const float* x = (const float*)d_in[0];
  const float* pos = (const float*)d_in[1];
  const float* w1 = (const float*)d_in[2];
  const float* gamma1 = (const float*)d_in[3];
  const float* beta1 = (const float*)d_in[4];
  const float* mean1 = (const float*)d_in[5];
  const float* var1 = (const float*)d_in[6];
  const float* w2 = (const float*)d_in[7];
  const float* gamma2 = (const float*)d_in[8];
  const float* beta2 = (const float*)d_in[9];
  const float* mean2 = (const float*)d_in[10];
  const float* var2 = (const float*)d_in[11];
  float* out = (float*)d_out;

  // ws layout (~70 MB): cand (16.8MB u32) and Tb (16.8MB u16) both live.
  float* ws = (float*)d_ws;
  float* s2 = ws;                                            // 768
  float* sh2 = s2 + 768;                                     // 768
  float* sqv = sh2 + 768;                                    // 16384
  unsigned short* w1b = (unsigned short*)(sqv + 16384);      // 512*768 u16
  unsigned short* w2b = w1b + 512 * 768;                     // 768*256 u16
  int* idx = (int*)(w2b + 768 * 256);                        // 65536 int
  unsigned short* hb = (unsigned short*)(idx + 65536);       // 4*4096*768 u16
  unsigned short* pooledb = hb + (size_t)BB * NN * CC;       // 4*4096*256 u16
  unsigned* cand = (unsigned*)(pooledb + (size_t)BB * NN * 256);  // 4.19M u32
  unsigned short* Tb = (unsigned short*)(cand + (size_t)BB * NN * 256);

  k_prep<<<BB * NN, 192, 0, stream>>>(x, pos, hb, sqv);
  k_wprep<<<2307, 256, 0, stream>>>(w1, w2, gamma2, beta2, mean2, var2,
                                    w1b, w2b, s2, sh2);
  k_gram<<<BB * 528, 256, 0, stream>>>(hb, sqv, cand);
  k_topk<<<BB * NN / 4, 256, 0, stream>>>(cand, x, pos, sqv, idx);
  k_mm<1><<<512, 256, 0, stream>>>(hb, w1b, Tb, nullptr, nullptr, CC, 512, 4);
  k_pool<<<BB * NN, 256, 0, stream>>>(Tb, idx, gamma1, beta1, mean1, var1, pooledb);
  k_mm<2><<<768, 256, 0, stream>>>(pooledb, w2b, out, s2, sh2, 256, CC, 6);
}